// Round 1
// baseline (759.470 us; speedup 1.0000x reference)
//
#include <hip/hip_runtime.h>

// Problem constants (match reference)
#define N_NODES 100000
#define N_EDGES 3200000
#define IN_F    128
#define HID     3
#define OUT_F   4

// d_ws layout (floats):
//   xw  : [N_NODES*3]  @ offset 0
//   deg : [N_NODES]    @ offset N_NODES*3   (becomes dinv in-place)
//   agg : [N_NODES*3]  @ offset N_NODES*4
// total = N_NODES*7 floats = 2.8 MB

__device__ inline float wave_reduce_sum(float v) {
    #pragma unroll
    for (int off = 32; off > 0; off >>= 1)
        v += __shfl_down(v, off, 64);
    return v;
}

// deg = 1.0 (self loop), agg = 0  (ws is poisoned to 0xAA each call)
__global__ void init_kernel(float* __restrict__ deg, float* __restrict__ agg) {
    int i = blockIdx.x * blockDim.x + threadIdx.x;
    if (i < N_NODES) {
        deg[i] = 1.0f;
        agg[i * 3 + 0] = 0.0f;
        agg[i * 3 + 1] = 0.0f;
        agg[i * 3 + 2] = 0.0f;
    }
}

// xw[n][0..2] = x[n][:] @ W   (one 64-lane wave per node, float2 loads)
__global__ void xw_kernel(const float* __restrict__ x,
                          const float* __restrict__ W,
                          float* __restrict__ xw) {
    int wave = threadIdx.x >> 6;   // 4 waves / 256-thread block
    int lane = threadIdx.x & 63;
    int node = blockIdx.x * 4 + wave;
    if (node >= N_NODES) return;

    float2 xv = *reinterpret_cast<const float2*>(x + (size_t)node * IN_F + lane * 2);
    const float* w = W + (lane * 2) * HID;   // rows 2*lane, 2*lane+1 of W[128][3]
    float s0 = xv.x * w[0] + xv.y * w[3];
    float s1 = xv.x * w[1] + xv.y * w[4];
    float s2 = xv.x * w[2] + xv.y * w[5];
    s0 = wave_reduce_sum(s0);
    s1 = wave_reduce_sum(s1);
    s2 = wave_reduce_sum(s2);
    if (lane == 0) {
        xw[node * 3 + 0] = s0;
        xw[node * 3 + 1] = s1;
        xw[node * 3 + 2] = s2;
    }
}

// deg[col[e]] += 1 over real edges
__global__ void deg_kernel(const int* __restrict__ col, float* __restrict__ deg) {
    for (int e = blockIdx.x * blockDim.x + threadIdx.x; e < N_EDGES;
         e += gridDim.x * blockDim.x) {
        atomicAdd(&deg[col[e]], 1.0f);
    }
}

// deg -> dinv in place (deg >= 1 always, self-loops included)
__global__ void dinv_kernel(float* __restrict__ deg) {
    int i = blockIdx.x * blockDim.x + threadIdx.x;
    if (i < N_NODES) deg[i] = rsqrtf(deg[i]);
}

// agg[col] += xw[row] * dinv[row]*dinv[col]  over real edges
__global__ void scatter_kernel(const int* __restrict__ row,
                               const int* __restrict__ col,
                               const float* __restrict__ xw,
                               const float* __restrict__ dinv,
                               float* __restrict__ agg) {
    for (int e = blockIdx.x * blockDim.x + threadIdx.x; e < N_EDGES;
         e += gridDim.x * blockDim.x) {
        int r = row[e];
        int c = col[e];
        float nrm = dinv[r] * dinv[c];
        atomicAdd(&agg[c * 3 + 0], xw[r * 3 + 0] * nrm);
        atomicAdd(&agg[c * 3 + 1], xw[r * 3 + 1] * nrm);
        atomicAdd(&agg[c * 3 + 2], xw[r * 3 + 2] * nrm);
    }
}

// h = relu(agg + selfloop + b); z = h @ Wout + bout; write both outputs
__global__ void out_kernel(const float* __restrict__ xw,
                           const float* __restrict__ dinv,
                           const float* __restrict__ agg,
                           const float* __restrict__ b,
                           const float* __restrict__ Wout,
                           const float* __restrict__ bout,
                           float* __restrict__ out) {
    int i = blockIdx.x * blockDim.x + threadIdx.x;
    if (i >= N_NODES) return;
    float di = dinv[i];
    float self = di * di;   // self-loop norm: dinv[i]*dinv[i]
    float h[3];
    #pragma unroll
    for (int j = 0; j < 3; ++j) {
        float a = agg[i * 3 + j] + xw[i * 3 + j] * self + b[j];
        h[j] = fmaxf(a, 0.0f);
        out[i * 3 + j] = h[j];
    }
    float* z = out + (size_t)N_NODES * 3;
    #pragma unroll
    for (int k = 0; k < 4; ++k) {
        float acc = bout[k];
        #pragma unroll
        for (int j = 0; j < 3; ++j) acc += h[j] * Wout[j * 4 + k];
        z[i * 4 + k] = acc;
    }
}

extern "C" void kernel_launch(void* const* d_in, const int* in_sizes, int n_in,
                              void* d_out, int out_size, void* d_ws, size_t ws_size,
                              hipStream_t stream) {
    const float* x    = (const float*)d_in[0];
    const int*   ei   = (const int*)d_in[1];   // [2, N_EDGES]: row then col
    const float* W    = (const float*)d_in[2];
    const float* b    = (const float*)d_in[3];
    const float* Wout = (const float*)d_in[4];
    const float* bout = (const float*)d_in[5];
    float* out = (float*)d_out;

    float* ws   = (float*)d_ws;
    float* xw   = ws;                       // N_NODES*3
    float* deg  = ws + (size_t)N_NODES * 3; // N_NODES (becomes dinv)
    float* agg  = ws + (size_t)N_NODES * 4; // N_NODES*3

    const int* row = ei;
    const int* col = ei + N_EDGES;

    const int B = 256;
    int gridN = (N_NODES + B - 1) / B;          // per-node kernels
    int gridE = 2048;                            // grid-stride over edges
    int gridX = (N_NODES + 3) / 4;               // xw: 4 nodes per block

    init_kernel<<<gridN, B, 0, stream>>>(deg, agg);
    xw_kernel<<<gridX, B, 0, stream>>>(x, W, xw);
    deg_kernel<<<gridE, B, 0, stream>>>(col, deg);
    dinv_kernel<<<gridN, B, 0, stream>>>(deg);
    scatter_kernel<<<gridE, B, 0, stream>>>(row, col, xw, deg, agg);
    out_kernel<<<gridN, B, 0, stream>>>(xw, deg, agg, b, Wout, bout, out);
}

// Round 2
// 384.038 us; speedup vs baseline: 1.9776x; 1.9776x over previous
//
#include <hip/hip_runtime.h>

// Problem constants (match reference)
#define N_NODES 100000
#define N_EDGES 3200000
#define IN_F    128
#define HID     3
#define OUT_F   4

// Counting-sort parameters
#define R        8                      // counter replication per destination
#define NCNT     (N_NODES * R)          // 800000 counters
#define SCAN_ITEMS 16
#define SCAN_BLOCK 256
#define SCAN_PER_BLOCK (SCAN_ITEMS * SCAN_BLOCK)                 // 4096
#define SCAN_NBLK ((NCNT + SCAN_PER_BLOCK - 1) / SCAN_PER_BLOCK) // 196

// d_ws layout (bytes):
//   cnt    : NCNT ints            (3.2 MB)  -> becomes exclusive-scan bases
//   rank   : N_EDGES ints         (12.8 MB)
//   srcIdx : N_EDGES ints         (12.8 MB)
//   xw     : N_NODES*3 floats     (1.2 MB)
//   dinv   : N_NODES floats       (0.4 MB)
//   bsum   : SCAN_NBLK ints       (<1 KB)
// total ~30.5 MB

__device__ inline float wave_reduce_sum(float v) {
    #pragma unroll
    for (int off = 32; off > 0; off >>= 1)
        v += __shfl_down(v, off, 64);
    return v;
}

// ---------------- xw = x @ W : one 64-lane wave per node ----------------
__global__ void xw_kernel(const float* __restrict__ x,
                          const float* __restrict__ W,
                          float* __restrict__ xw) {
    int wave = threadIdx.x >> 6;
    int lane = threadIdx.x & 63;
    int node = blockIdx.x * 4 + wave;
    if (node >= N_NODES) return;

    float2 xv = *reinterpret_cast<const float2*>(x + (size_t)node * IN_F + lane * 2);
    const float* w = W + (lane * 2) * HID;
    float s0 = xv.x * w[0] + xv.y * w[3];
    float s1 = xv.x * w[1] + xv.y * w[4];
    float s2 = xv.x * w[2] + xv.y * w[5];
    s0 = wave_reduce_sum(s0);
    s1 = wave_reduce_sum(s1);
    s2 = wave_reduce_sum(s2);
    if (lane == 0) {
        xw[node * 3 + 0] = s0;
        xw[node * 3 + 1] = s1;
        xw[node * 3 + 2] = s2;
    }
}

// ---------------- pass 1: count + per-edge rank (replicated counters) ----
__global__ void count_kernel(const int* __restrict__ col,
                             int* __restrict__ cnt,
                             int* __restrict__ rank) {
    int e = blockIdx.x * blockDim.x + threadIdx.x;
    if (e >= N_EDGES) return;
    int c = col[e];
    rank[e] = atomicAdd(&cnt[c * R + (e & (R - 1))], 1);
}

// ---------------- pass 2: exclusive scan over cnt[NCNT] ------------------
__global__ void scan1_kernel(int* __restrict__ data, int* __restrict__ bsum) {
    __shared__ int s[SCAN_BLOCK];
    int tid = threadIdx.x;
    int base = blockIdx.x * SCAN_PER_BLOCK + tid * SCAN_ITEMS;
    int v[SCAN_ITEMS];
    int tsum = 0;
    #pragma unroll
    for (int j = 0; j < SCAN_ITEMS; ++j) {
        v[j] = (base + j < NCNT) ? data[base + j] : 0;
        tsum += v[j];
    }
    s[tid] = tsum;
    __syncthreads();
    // Hillis-Steele inclusive scan of per-thread sums
    for (int off = 1; off < SCAN_BLOCK; off <<= 1) {
        int t = (tid >= off) ? s[tid - off] : 0;
        __syncthreads();
        s[tid] += t;
        __syncthreads();
    }
    int run = s[tid] - tsum;   // exclusive prefix for this thread
    #pragma unroll
    for (int j = 0; j < SCAN_ITEMS; ++j) {
        int t = v[j];
        if (base + j < NCNT) data[base + j] = run;
        run += t;
    }
    if (tid == SCAN_BLOCK - 1) bsum[blockIdx.x] = s[SCAN_BLOCK - 1];
}

__global__ void scan2_kernel(int* __restrict__ bsum) {
    __shared__ int s[SCAN_BLOCK];
    int tid = threadIdx.x;
    int v = (tid < SCAN_NBLK) ? bsum[tid] : 0;
    s[tid] = v;
    __syncthreads();
    for (int off = 1; off < SCAN_BLOCK; off <<= 1) {
        int t = (tid >= off) ? s[tid - off] : 0;
        __syncthreads();
        s[tid] += t;
        __syncthreads();
    }
    if (tid < SCAN_NBLK) bsum[tid] = s[tid] - v;   // exclusive
}

__global__ void scan3_kernel(int* __restrict__ data, const int* __restrict__ bsum) {
    int i = blockIdx.x * blockDim.x + threadIdx.x;
    if (i < NCNT) data[i] += bsum[i / SCAN_PER_BLOCK];
}

// ---------------- dinv from scanned bases --------------------------------
__global__ void dinv_kernel(const int* __restrict__ cnt, float* __restrict__ dinv) {
    int c = blockIdx.x * blockDim.x + threadIdx.x;
    if (c >= N_NODES) return;
    int start = cnt[c * R];
    int end   = (c == N_NODES - 1) ? N_EDGES : cnt[(c + 1) * R];
    float deg = (float)(end - start + 1);   // +1 self loop
    dinv[c] = rsqrtf(deg);
}

// ---------------- pass 3: CSR fill (no atomics) --------------------------
__global__ void fill_kernel(const int* __restrict__ row,
                            const int* __restrict__ col,
                            const int* __restrict__ cnt,
                            const int* __restrict__ rank,
                            int* __restrict__ srcIdx) {
    int e = blockIdx.x * blockDim.x + threadIdx.x;
    if (e >= N_EDGES) return;
    int c = col[e];
    int pos = cnt[c * R + (e & (R - 1))] + rank[e];
    srcIdx[pos] = row[e];
}

// ---------------- pass 4: segment sum + full epilogue --------------------
__global__ void segout_kernel(const int* __restrict__ cnt,
                              const int* __restrict__ srcIdx,
                              const float* __restrict__ xw,
                              const float* __restrict__ dinv,
                              const float* __restrict__ b,
                              const float* __restrict__ Wout,
                              const float* __restrict__ bout,
                              float* __restrict__ out) {
    int c = blockIdx.x * blockDim.x + threadIdx.x;
    if (c >= N_NODES) return;
    int start = cnt[c * R];
    int end   = (c == N_NODES - 1) ? N_EDGES : cnt[(c + 1) * R];
    float a0 = 0.f, a1 = 0.f, a2 = 0.f;
    for (int i = start; i < end; ++i) {
        int r = srcIdx[i];
        float dr = dinv[r];
        a0 += xw[r * 3 + 0] * dr;
        a1 += xw[r * 3 + 1] * dr;
        a2 += xw[r * 3 + 2] * dr;
    }
    float di = dinv[c];
    float sl = di * di;   // self-loop norm
    float h0 = fmaxf(a0 * di + xw[c * 3 + 0] * sl + b[0], 0.f);
    float h1 = fmaxf(a1 * di + xw[c * 3 + 1] * sl + b[1], 0.f);
    float h2 = fmaxf(a2 * di + xw[c * 3 + 2] * sl + b[2], 0.f);
    out[c * 3 + 0] = h0;
    out[c * 3 + 1] = h1;
    out[c * 3 + 2] = h2;
    float* z = out + (size_t)N_NODES * 3;
    #pragma unroll
    for (int k = 0; k < 4; ++k) {
        z[c * 4 + k] = bout[k] + h0 * Wout[0 * 4 + k] + h1 * Wout[1 * 4 + k]
                                 + h2 * Wout[2 * 4 + k];
    }
}

extern "C" void kernel_launch(void* const* d_in, const int* in_sizes, int n_in,
                              void* d_out, int out_size, void* d_ws, size_t ws_size,
                              hipStream_t stream) {
    const float* x    = (const float*)d_in[0];
    const int*   ei   = (const int*)d_in[1];   // [2, N_EDGES]: row then col
    const float* W    = (const float*)d_in[2];
    const float* b    = (const float*)d_in[3];
    const float* Wout = (const float*)d_in[4];
    const float* bout = (const float*)d_in[5];
    float* out = (float*)d_out;

    char* wsb = (char*)d_ws;
    int*   cnt    = (int*)(wsb);                                   // 3.2 MB
    int*   rank   = (int*)(wsb + (size_t)NCNT * 4);                // 12.8 MB
    int*   srcIdx = (int*)(wsb + (size_t)NCNT * 4 + (size_t)N_EDGES * 4);
    float* xw     = (float*)(wsb + (size_t)NCNT * 4 + (size_t)N_EDGES * 8);
    float* dinv   = (float*)((char*)xw + (size_t)N_NODES * 3 * 4);
    int*   bsum   = (int*)((char*)dinv + (size_t)N_NODES * 4);

    const int* row = ei;
    const int* col = ei + N_EDGES;

    const int B = 256;
    int gridN = (N_NODES + B - 1) / B;
    int gridE = (N_EDGES + B - 1) / B;
    int gridX = (N_NODES + 3) / 4;
    int gridS3 = (NCNT + B - 1) / B;

    hipMemsetAsync(cnt, 0, (size_t)NCNT * 4, stream);
    xw_kernel<<<gridX, B, 0, stream>>>(x, W, xw);
    count_kernel<<<gridE, B, 0, stream>>>(col, cnt, rank);
    scan1_kernel<<<SCAN_NBLK, SCAN_BLOCK, 0, stream>>>(cnt, bsum);
    scan2_kernel<<<1, SCAN_BLOCK, 0, stream>>>(bsum);
    scan3_kernel<<<gridS3, B, 0, stream>>>(cnt, bsum);
    dinv_kernel<<<gridN, B, 0, stream>>>(cnt, dinv);
    fill_kernel<<<gridE, B, 0, stream>>>(row, col, cnt, rank, srcIdx);
    segout_kernel<<<gridN, B, 0, stream>>>(cnt, srcIdx, xw, dinv, b, Wout, bout, out);
}

// Round 3
// 260.492 us; speedup vs baseline: 2.9155x; 1.4743x over previous
//
#include <hip/hip_runtime.h>

// Problem constants (match reference)
#define N_NODES 100000
#define N_EDGES 3200000
#define IN_F    128
#define HID     3
#define OUT_F   4

// Bucketed partition parameters
#define BSHIFT  7
#define BSIZE   128                                  // dest nodes per bucket
#define NBUCK   ((N_NODES + BSIZE - 1) / BSIZE)      // 782
#define NBLKA   512                                  // partition blocks
#define EPB     ((N_EDGES + NBLKA - 1) / NBLKA)      // 6250 edges per block
#define NH      (NBUCK * NBLKA)                      // 400384 hist entries

#define SCAN_ITEMS 16
#define SCAN_BLOCK 256
#define SCAN_PER_BLOCK (SCAN_ITEMS * SCAN_BLOCK)                 // 4096
#define NS1 ((NH + SCAN_PER_BLOCK - 1) / SCAN_PER_BLOCK)         // 98

// d_ws layout (bytes):
//   histG  : NH ints              (1.6 MB)  bucket-major [bucket][block]
//   packed : N_EDGES ints         (12.8 MB) bucket-sorted (row<<7 | col&127)
//   xw     : N_NODES*3 floats     (1.2 MB)
//   xwn4   : N_NODES float4       (1.6 MB)  xw[r]*dinv[r], padded for 16B gather
//   dinv   : N_NODES floats       (0.4 MB)
//   bsum   : NS1 ints
// total ~17.6 MB

__device__ inline float wave_reduce_sum(float v) {
    #pragma unroll
    for (int off = 32; off > 0; off >>= 1)
        v += __shfl_down(v, off, 64);
    return v;
}

// ---------------- xw = x @ W : one 64-lane wave per node ----------------
__global__ void xw_kernel(const float* __restrict__ x,
                          const float* __restrict__ W,
                          float* __restrict__ xw) {
    int wave = threadIdx.x >> 6;
    int lane = threadIdx.x & 63;
    int node = blockIdx.x * 4 + wave;
    if (node >= N_NODES) return;

    float2 xv = *reinterpret_cast<const float2*>(x + (size_t)node * IN_F + lane * 2);
    const float* w = W + (lane * 2) * HID;
    float s0 = xv.x * w[0] + xv.y * w[3];
    float s1 = xv.x * w[1] + xv.y * w[4];
    float s2 = xv.x * w[2] + xv.y * w[5];
    s0 = wave_reduce_sum(s0);
    s1 = wave_reduce_sum(s1);
    s2 = wave_reduce_sum(s2);
    if (lane == 0) {
        xw[node * 3 + 0] = s0;
        xw[node * 3 + 1] = s1;
        xw[node * 3 + 2] = s2;
    }
}

// ---------- pass A: per-block LDS histogram over coarse buckets ----------
__global__ void histA_kernel(const int* __restrict__ col, int* __restrict__ histG) {
    __shared__ int hist[NBUCK];
    int tid = threadIdx.x, blk = blockIdx.x;
    for (int i = tid; i < NBUCK; i += 256) hist[i] = 0;
    __syncthreads();
    int start = blk * EPB, end = min(start + EPB, N_EDGES);
    for (int e = start + tid; e < end; e += 256)
        atomicAdd(&hist[col[e] >> BSHIFT], 1);
    __syncthreads();
    for (int i = tid; i < NBUCK; i += 256)
        histG[i * NBLKA + blk] = hist[i];   // bucket-major
}

// ---------------- exclusive scan over histG[NH] --------------------------
__global__ void scan1_kernel(int* __restrict__ data, int* __restrict__ bsum) {
    __shared__ int s[SCAN_BLOCK];
    int tid = threadIdx.x;
    int base = blockIdx.x * SCAN_PER_BLOCK + tid * SCAN_ITEMS;
    int v[SCAN_ITEMS];
    int tsum = 0;
    #pragma unroll
    for (int j = 0; j < SCAN_ITEMS; ++j) {
        v[j] = (base + j < NH) ? data[base + j] : 0;
        tsum += v[j];
    }
    s[tid] = tsum;
    __syncthreads();
    for (int off = 1; off < SCAN_BLOCK; off <<= 1) {
        int t = (tid >= off) ? s[tid - off] : 0;
        __syncthreads();
        s[tid] += t;
        __syncthreads();
    }
    int run = s[tid] - tsum;
    #pragma unroll
    for (int j = 0; j < SCAN_ITEMS; ++j) {
        int t = v[j];
        if (base + j < NH) data[base + j] = run;
        run += t;
    }
    if (tid == SCAN_BLOCK - 1) bsum[blockIdx.x] = s[SCAN_BLOCK - 1];
}

__global__ void scan2_kernel(int* __restrict__ bsum) {
    __shared__ int s[SCAN_BLOCK];
    int tid = threadIdx.x;
    int v = (tid < NS1) ? bsum[tid] : 0;
    s[tid] = v;
    __syncthreads();
    for (int off = 1; off < SCAN_BLOCK; off <<= 1) {
        int t = (tid >= off) ? s[tid - off] : 0;
        __syncthreads();
        s[tid] += t;
        __syncthreads();
    }
    if (tid < NS1) bsum[tid] = s[tid] - v;
}

__global__ void scan3_kernel(int* __restrict__ data, const int* __restrict__ bsum) {
    int i = blockIdx.x * blockDim.x + threadIdx.x;
    if (i < NH) data[i] += bsum[i / SCAN_PER_BLOCK];
}

// ---------- pass B: scatter packed edges into bucket-sorted order --------
__global__ void fillB_kernel(const int* __restrict__ row,
                             const int* __restrict__ col,
                             const int* __restrict__ histG,
                             int* __restrict__ packed) {
    __shared__ int offs[NBUCK];
    int tid = threadIdx.x, blk = blockIdx.x;
    for (int i = tid; i < NBUCK; i += 256) offs[i] = histG[i * NBLKA + blk];
    __syncthreads();
    int start = blk * EPB, end = min(start + EPB, N_EDGES);
    for (int e = start + tid; e < end; e += 256) {
        int c = col[e], r = row[e];
        int b = c >> BSHIFT;
        int pos = atomicAdd(&offs[b], 1);   // LDS atomic
        packed[pos] = (r << BSHIFT) | (c & (BSIZE - 1));
    }
}

// ---------- C1: per-dest degree via LDS counters -> dinv -----------------
__global__ void degC_kernel(const int* __restrict__ histG,
                            const int* __restrict__ packed,
                            float* __restrict__ dinv) {
    __shared__ int cnt[BSIZE];
    int tid = threadIdx.x, b = blockIdx.x;
    if (tid < BSIZE) cnt[tid] = 0;
    __syncthreads();
    int start = histG[b * NBLKA];
    int end   = (b + 1 < NBUCK) ? histG[(b + 1) * NBLKA] : N_EDGES;
    for (int i = start + tid; i < end; i += 256)
        atomicAdd(&cnt[packed[i] & (BSIZE - 1)], 1);
    __syncthreads();
    if (tid < BSIZE) {
        int node = b * BSIZE + tid;
        if (node < N_NODES) dinv[node] = rsqrtf((float)(cnt[tid] + 1));  // +1 self loop
    }
}

// ---------- xwn4[r] = xw[r] * dinv[r] (padded float4 for 16B gathers) ----
__global__ void xwn_kernel(const float* __restrict__ xw,
                           const float* __restrict__ dinv,
                           float4* __restrict__ xwn4) {
    int i = blockIdx.x * blockDim.x + threadIdx.x;
    if (i < N_NODES) {
        float d = dinv[i];
        xwn4[i] = make_float4(xw[i * 3 + 0] * d, xw[i * 3 + 1] * d,
                              xw[i * 3 + 2] * d, 0.f);
    }
}

// ---------- C2: bucket aggregation in LDS + fused epilogue ---------------
// agg_c = dinv[c] * (sum_{r in N(c)} xwn[r] + xwn[c])   (self loop folded in)
__global__ void aggC_kernel(const int* __restrict__ histG,
                            const int* __restrict__ packed,
                            const float4* __restrict__ xwn4,
                            const float* __restrict__ dinv,
                            const float* __restrict__ bb,
                            const float* __restrict__ Wout,
                            const float* __restrict__ bout,
                            float* __restrict__ out) {
    __shared__ float acc[BSIZE * 3];
    int tid = threadIdx.x, b = blockIdx.x;
    for (int i = tid; i < BSIZE * 3; i += 256) acc[i] = 0.f;
    __syncthreads();
    int start = histG[b * NBLKA];
    int end   = (b + 1 < NBUCK) ? histG[(b + 1) * NBLKA] : N_EDGES;
    for (int i = start + tid; i < end; i += 256) {
        int p  = packed[i];
        int r  = p >> BSHIFT;
        int cl = p & (BSIZE - 1);
        float4 v = xwn4[r];
        atomicAdd(&acc[cl * 3 + 0], v.x);
        atomicAdd(&acc[cl * 3 + 1], v.y);
        atomicAdd(&acc[cl * 3 + 2], v.z);
    }
    __syncthreads();
    if (tid < BSIZE) {
        int node = b * BSIZE + tid;
        if (node < N_NODES) {
            float di = dinv[node];
            float4 s = xwn4[node];
            float h0 = fmaxf((acc[tid * 3 + 0] + s.x) * di + bb[0], 0.f);
            float h1 = fmaxf((acc[tid * 3 + 1] + s.y) * di + bb[1], 0.f);
            float h2 = fmaxf((acc[tid * 3 + 2] + s.z) * di + bb[2], 0.f);
            out[node * 3 + 0] = h0;
            out[node * 3 + 1] = h1;
            out[node * 3 + 2] = h2;
            float* z = out + (size_t)N_NODES * 3;
            #pragma unroll
            for (int k = 0; k < 4; ++k) {
                z[node * 4 + k] = bout[k] + h0 * Wout[0 * 4 + k]
                                          + h1 * Wout[1 * 4 + k]
                                          + h2 * Wout[2 * 4 + k];
            }
        }
    }
}

extern "C" void kernel_launch(void* const* d_in, const int* in_sizes, int n_in,
                              void* d_out, int out_size, void* d_ws, size_t ws_size,
                              hipStream_t stream) {
    const float* x    = (const float*)d_in[0];
    const int*   ei   = (const int*)d_in[1];   // [2, N_EDGES]: row then col
    const float* W    = (const float*)d_in[2];
    const float* b    = (const float*)d_in[3];
    const float* Wout = (const float*)d_in[4];
    const float* bout = (const float*)d_in[5];
    float* out = (float*)d_out;

    char* wsb = (char*)d_ws;
    int*    histG  = (int*)(wsb);
    int*    packed = (int*)(wsb + (size_t)NH * 4);
    float*  xw     = (float*)(wsb + (size_t)NH * 4 + (size_t)N_EDGES * 4);
    float4* xwn4   = (float4*)((char*)xw + (size_t)N_NODES * 3 * 4);
    float*  dinv   = (float*)((char*)xwn4 + (size_t)N_NODES * 16);
    int*    bsum   = (int*)((char*)dinv + (size_t)N_NODES * 4);

    const int* row = ei;
    const int* col = ei + N_EDGES;

    const int B = 256;
    int gridN  = (N_NODES + B - 1) / B;
    int gridX  = (N_NODES + 3) / 4;
    int gridS3 = (NH + B - 1) / B;

    xw_kernel<<<gridX, B, 0, stream>>>(x, W, xw);
    histA_kernel<<<NBLKA, B, 0, stream>>>(col, histG);
    scan1_kernel<<<NS1, SCAN_BLOCK, 0, stream>>>(histG, bsum);
    scan2_kernel<<<1, SCAN_BLOCK, 0, stream>>>(bsum);
    scan3_kernel<<<gridS3, B, 0, stream>>>(histG, bsum);
    fillB_kernel<<<NBLKA, B, 0, stream>>>(row, col, histG, packed);
    degC_kernel<<<NBUCK, B, 0, stream>>>(histG, packed, dinv);
    xwn_kernel<<<gridN, B, 0, stream>>>(xw, dinv, xwn4);
    aggC_kernel<<<NBUCK, B, 0, stream>>>(histG, packed, xwn4, dinv, b, Wout, bout, out);
}

// Round 4
// 233.119 us; speedup vs baseline: 3.2579x; 1.1174x over previous
//
#include <hip/hip_runtime.h>

// Problem constants (match reference)
#define N_NODES 100000
#define N_EDGES 3200000
#define IN_F    128
#define HID     3
#define OUT_F   4

// Bucketed partition parameters
#define BSHIFT  7
#define BSIZE   128                                  // dest nodes per bucket
#define NBUCK   ((N_NODES + BSIZE - 1) / BSIZE)      // 782
#define NBLKA   512                                  // partition blocks
#define EPB     ((N_EDGES + NBLKA - 1) / NBLKA)      // 6250 edges per block
#define NH      (NBUCK * NBLKA)                      // 400384 hist entries

#define SCAN_ITEMS 16
#define SCAN_BLOCK 256
#define SCAN_PER_BLOCK (SCAN_ITEMS * SCAN_BLOCK)                 // 4096
#define NS1 ((NH + SCAN_PER_BLOCK - 1) / SCAN_PER_BLOCK)         // 98

// d_ws layout (bytes):
//   histG  : NH ints              (1.6 MB)  bucket-major [bucket][block]
//   packed : N_EDGES ints         (12.8 MB) bucket-sorted (row<<7 | col&127)
//   xw     : N_NODES*3 floats     (1.2 MB)
//   xwn4   : N_NODES float4       (1.6 MB)  {xw*dinv, dinv} per node
//   bsum   : NS1 ints
// total ~17.2 MB

// ---------------- xw = x @ W : 2 nodes per 64-lane wave, float4 loads ----
__global__ void xw_kernel(const float* __restrict__ x,
                          const float* __restrict__ W,
                          float* __restrict__ xw) {
    int wave = threadIdx.x >> 6;        // 4 waves / block
    int lane = threadIdx.x & 63;
    int half = lane >> 5;               // which node within the wave
    int l    = lane & 31;               // 32 lanes x float4 = 128 elems
    int node = blockIdx.x * 8 + wave * 2 + half;
    if (node >= N_NODES) return;

    float4 xv = *reinterpret_cast<const float4*>(x + (size_t)node * IN_F + l * 4);
    const float* w = W + l * 4 * HID;   // rows 4l..4l+3 of W[128][3]
    float s0 = xv.x * w[0] + xv.y * w[3] + xv.z * w[6] + xv.w * w[9];
    float s1 = xv.x * w[1] + xv.y * w[4] + xv.z * w[7] + xv.w * w[10];
    float s2 = xv.x * w[2] + xv.y * w[5] + xv.z * w[8] + xv.w * w[11];
    #pragma unroll
    for (int off = 16; off > 0; off >>= 1) {
        s0 += __shfl_down(s0, off, 32);
        s1 += __shfl_down(s1, off, 32);
        s2 += __shfl_down(s2, off, 32);
    }
    if (l == 0) {
        xw[node * 3 + 0] = s0;
        xw[node * 3 + 1] = s1;
        xw[node * 3 + 2] = s2;
    }
}

// ---------- pass A: per-block LDS histogram over coarse buckets ----------
__global__ void histA_kernel(const int* __restrict__ col, int* __restrict__ histG) {
    __shared__ int hist[NBUCK];
    int tid = threadIdx.x, blk = blockIdx.x;
    for (int i = tid; i < NBUCK; i += 256) hist[i] = 0;
    __syncthreads();
    int start = blk * EPB, end = min(start + EPB, N_EDGES);
    for (int e = start + tid; e < end; e += 256)
        atomicAdd(&hist[col[e] >> BSHIFT], 1);
    __syncthreads();
    for (int i = tid; i < NBUCK; i += 256)
        histG[i * NBLKA + blk] = hist[i];   // bucket-major
}

// ---------------- exclusive scan over histG[NH] --------------------------
__global__ void scan1_kernel(int* __restrict__ data, int* __restrict__ bsum) {
    __shared__ int s[SCAN_BLOCK];
    int tid = threadIdx.x;
    int base = blockIdx.x * SCAN_PER_BLOCK + tid * SCAN_ITEMS;
    int v[SCAN_ITEMS];
    int tsum = 0;
    #pragma unroll
    for (int j = 0; j < SCAN_ITEMS; ++j) {
        v[j] = (base + j < NH) ? data[base + j] : 0;
        tsum += v[j];
    }
    s[tid] = tsum;
    __syncthreads();
    for (int off = 1; off < SCAN_BLOCK; off <<= 1) {
        int t = (tid >= off) ? s[tid - off] : 0;
        __syncthreads();
        s[tid] += t;
        __syncthreads();
    }
    int run = s[tid] - tsum;
    #pragma unroll
    for (int j = 0; j < SCAN_ITEMS; ++j) {
        int t = v[j];
        if (base + j < NH) data[base + j] = run;
        run += t;
    }
    if (tid == SCAN_BLOCK - 1) bsum[blockIdx.x] = s[SCAN_BLOCK - 1];
}

__global__ void scan2_kernel(int* __restrict__ bsum) {
    __shared__ int s[SCAN_BLOCK];
    int tid = threadIdx.x;
    int v = (tid < NS1) ? bsum[tid] : 0;
    s[tid] = v;
    __syncthreads();
    for (int off = 1; off < SCAN_BLOCK; off <<= 1) {
        int t = (tid >= off) ? s[tid - off] : 0;
        __syncthreads();
        s[tid] += t;
        __syncthreads();
    }
    if (tid < NS1) bsum[tid] = s[tid] - v;
}

__global__ void scan3_kernel(int* __restrict__ data, const int* __restrict__ bsum) {
    int i = blockIdx.x * blockDim.x + threadIdx.x;
    if (i < NH) data[i] += bsum[i / SCAN_PER_BLOCK];
}

// ---------- pass B: scatter packed edges into bucket-sorted order --------
__global__ void fillB_kernel(const int* __restrict__ row,
                             const int* __restrict__ col,
                             const int* __restrict__ histG,
                             int* __restrict__ packed) {
    __shared__ int offs[NBUCK];
    int tid = threadIdx.x, blk = blockIdx.x;
    for (int i = tid; i < NBUCK; i += 256) offs[i] = histG[i * NBLKA + blk];
    __syncthreads();
    int start = blk * EPB, end = min(start + EPB, N_EDGES);
    for (int e = start + tid; e < end; e += 256) {
        int c = col[e], r = row[e];
        int b = c >> BSHIFT;
        int pos = atomicAdd(&offs[b], 1);   // LDS atomic
        packed[pos] = (r << BSHIFT) | (c & (BSIZE - 1));
    }
}

// ---------- C1: per-dest degree + fused xwn: xwn4[n] = {xw[n]*d, d} ------
__global__ __launch_bounds__(512) void degC_kernel(const int* __restrict__ histG,
                                                   const int* __restrict__ packed,
                                                   const float* __restrict__ xw,
                                                   float4* __restrict__ xwn4) {
    __shared__ int cnt[BSIZE];
    int tid = threadIdx.x, b = blockIdx.x;
    if (tid < BSIZE) cnt[tid] = 0;
    __syncthreads();
    int start = histG[b * NBLKA];
    int end   = (b + 1 < NBUCK) ? histG[(b + 1) * NBLKA] : N_EDGES;
    int len   = end - start;
    int nfull = len & ~(4 * 512 - 1);
    for (int off = tid; off < nfull; off += 2048) {
        int p0 = packed[start + off];
        int p1 = packed[start + off + 512];
        int p2 = packed[start + off + 1024];
        int p3 = packed[start + off + 1536];
        atomicAdd(&cnt[p0 & (BSIZE - 1)], 1);
        atomicAdd(&cnt[p1 & (BSIZE - 1)], 1);
        atomicAdd(&cnt[p2 & (BSIZE - 1)], 1);
        atomicAdd(&cnt[p3 & (BSIZE - 1)], 1);
    }
    for (int off = nfull + tid; off < len; off += 512)
        atomicAdd(&cnt[packed[start + off] & (BSIZE - 1)], 1);
    __syncthreads();
    if (tid < BSIZE) {
        int node = b * BSIZE + tid;
        if (node < N_NODES) {
            float d = rsqrtf((float)(cnt[tid] + 1));   // +1 self loop
            xwn4[node] = make_float4(xw[node * 3 + 0] * d,
                                     xw[node * 3 + 1] * d,
                                     xw[node * 3 + 2] * d, d);
        }
    }
}

// ---------- C2: bucket aggregation in LDS + fused epilogue ---------------
// agg_c = dinv[c] * (sum_{r in N(c)} xwn[r] + xwn[c])   (self loop folded in)
__global__ __launch_bounds__(512) void aggC_kernel(const int* __restrict__ histG,
                                                   const int* __restrict__ packed,
                                                   const float4* __restrict__ xwn4,
                                                   const float* __restrict__ bb,
                                                   const float* __restrict__ Wout,
                                                   const float* __restrict__ bout,
                                                   float* __restrict__ out) {
    __shared__ float acc[BSIZE * 3];
    int tid = threadIdx.x, b = blockIdx.x;
    for (int i = tid; i < BSIZE * 3; i += 512) acc[i] = 0.f;
    __syncthreads();
    int start = histG[b * NBLKA];
    int end   = (b + 1 < NBUCK) ? histG[(b + 1) * NBLKA] : N_EDGES;
    int len   = end - start;
    int nfull = len & ~(4 * 512 - 1);
    for (int off = tid; off < nfull; off += 2048) {
        int p0 = packed[start + off];
        int p1 = packed[start + off + 512];
        int p2 = packed[start + off + 1024];
        int p3 = packed[start + off + 1536];
        float4 v0 = xwn4[p0 >> BSHIFT];
        float4 v1 = xwn4[p1 >> BSHIFT];
        float4 v2 = xwn4[p2 >> BSHIFT];
        float4 v3 = xwn4[p3 >> BSHIFT];
        int c0 = (p0 & (BSIZE - 1)) * 3, c1 = (p1 & (BSIZE - 1)) * 3;
        int c2 = (p2 & (BSIZE - 1)) * 3, c3 = (p3 & (BSIZE - 1)) * 3;
        atomicAdd(&acc[c0 + 0], v0.x); atomicAdd(&acc[c0 + 1], v0.y); atomicAdd(&acc[c0 + 2], v0.z);
        atomicAdd(&acc[c1 + 0], v1.x); atomicAdd(&acc[c1 + 1], v1.y); atomicAdd(&acc[c1 + 2], v1.z);
        atomicAdd(&acc[c2 + 0], v2.x); atomicAdd(&acc[c2 + 1], v2.y); atomicAdd(&acc[c2 + 2], v2.z);
        atomicAdd(&acc[c3 + 0], v3.x); atomicAdd(&acc[c3 + 1], v3.y); atomicAdd(&acc[c3 + 2], v3.z);
    }
    for (int off = nfull + tid; off < len; off += 512) {
        int p = packed[start + off];
        float4 v = xwn4[p >> BSHIFT];
        int c = (p & (BSIZE - 1)) * 3;
        atomicAdd(&acc[c + 0], v.x);
        atomicAdd(&acc[c + 1], v.y);
        atomicAdd(&acc[c + 2], v.z);
    }
    __syncthreads();
    if (tid < BSIZE) {
        int node = b * BSIZE + tid;
        if (node < N_NODES) {
            float4 s = xwn4[node];
            float di = s.w;
            float h0 = fmaxf((acc[tid * 3 + 0] + s.x) * di + bb[0], 0.f);
            float h1 = fmaxf((acc[tid * 3 + 1] + s.y) * di + bb[1], 0.f);
            float h2 = fmaxf((acc[tid * 3 + 2] + s.z) * di + bb[2], 0.f);
            out[node * 3 + 0] = h0;
            out[node * 3 + 1] = h1;
            out[node * 3 + 2] = h2;
            float* z = out + (size_t)N_NODES * 3;
            #pragma unroll
            for (int k = 0; k < 4; ++k) {
                z[node * 4 + k] = bout[k] + h0 * Wout[0 * 4 + k]
                                          + h1 * Wout[1 * 4 + k]
                                          + h2 * Wout[2 * 4 + k];
            }
        }
    }
}

extern "C" void kernel_launch(void* const* d_in, const int* in_sizes, int n_in,
                              void* d_out, int out_size, void* d_ws, size_t ws_size,
                              hipStream_t stream) {
    const float* x    = (const float*)d_in[0];
    const int*   ei   = (const int*)d_in[1];   // [2, N_EDGES]: row then col
    const float* W    = (const float*)d_in[2];
    const float* b    = (const float*)d_in[3];
    const float* Wout = (const float*)d_in[4];
    const float* bout = (const float*)d_in[5];
    float* out = (float*)d_out;

    char* wsb = (char*)d_ws;
    int*    histG  = (int*)(wsb);
    int*    packed = (int*)(wsb + (size_t)NH * 4);
    float*  xw     = (float*)(wsb + (size_t)NH * 4 + (size_t)N_EDGES * 4);
    float4* xwn4   = (float4*)((char*)xw + (size_t)N_NODES * 3 * 4);
    int*    bsum   = (int*)((char*)xwn4 + (size_t)N_NODES * 16);

    const int* row = ei;
    const int* col = ei + N_EDGES;

    const int B = 256;
    int gridX  = (N_NODES + 7) / 8;
    int gridS3 = (NH + B - 1) / B;

    xw_kernel<<<gridX, B, 0, stream>>>(x, W, xw);
    histA_kernel<<<NBLKA, B, 0, stream>>>(col, histG);
    scan1_kernel<<<NS1, SCAN_BLOCK, 0, stream>>>(histG, bsum);
    scan2_kernel<<<1, SCAN_BLOCK, 0, stream>>>(bsum);
    scan3_kernel<<<gridS3, B, 0, stream>>>(histG, bsum);
    fillB_kernel<<<NBLKA, B, 0, stream>>>(row, col, histG, packed);
    degC_kernel<<<NBUCK, 512, 0, stream>>>(histG, packed, xw, xwn4);
    aggC_kernel<<<NBUCK, 512, 0, stream>>>(histG, packed, xwn4, b, Wout, bout, out);
}